// Round 1
// baseline (502.572 us; speedup 1.0000x reference)
//
#include <hip/hip_runtime.h>

#define KNN    8
#define BLOCK  256
#define TILE   2048            // float4 per tile -> 32 KiB LDS
#define EPSW   1e-8f
#define BIGF   3.4e38f

// Sorted-descending top-8 insert; all indices compile-time -> stays in VGPRs.
__device__ __forceinline__ void insert8(float d2, int j, float bd[KNN], int bi[KNN]) {
    if (d2 < bd[0]) {
        bd[0] = d2; bi[0] = j;
#pragma unroll
        for (int t = 0; t < KNN - 1; t++) {
            if (bd[t] < bd[t + 1]) {
                float td = bd[t]; bd[t] = bd[t + 1]; bd[t + 1] = td;
                int   ti = bi[t]; bi[t] = bi[t + 1]; bi[t + 1] = ti;
            }
        }
    }
}

// Scan refs [tb, tb+cnt) staged in lds; maintain per-thread top-8.
__device__ __forceinline__ void scan_tile(const float4* lds, int cnt, int tb,
                                          float qx, float qy, float qz, float q2,
                                          float bd[KNN], int bi[KNN]) {
    if (cnt == TILE) {
#pragma unroll 8
        for (int i = 0; i < TILE; i++) {
            float4 p = lds[i];
            // match reference numerics: (q2 + r2) - 2*(q . r)
            float d2 = (q2 + p.w) - 2.0f * (qx * p.x + qy * p.y + qz * p.z);
            insert8(d2, tb + i, bd, bi);
        }
    } else {
        for (int i = 0; i < cnt; i++) {
            float4 p = lds[i];
            float d2 = (q2 + p.w) - 2.0f * (qx * p.x + qy * p.y + qz * p.z);
            insert8(d2, tb + i, bd, bi);
        }
    }
}

// Partial kernel: blockIdx.y selects an M-chunk; writes per-split top-8 to ws.
__global__ __launch_bounds__(BLOCK) void knn_partial(
    const float* __restrict__ q, const float* __restrict__ r,
    float* __restrict__ wsd, int* __restrict__ wsi,
    int N, int M, int S, int chunk) {
    __shared__ float4 lds[TILE];
    int qi = blockIdx.x * BLOCK + threadIdx.x;
    int s  = blockIdx.y;
    int base = s * chunk;
    int end  = min(M, base + chunk);

    float qx = 0.f, qy = 0.f, qz = 0.f, q2 = 0.f;
    if (qi < N) {
        qx = q[3 * qi]; qy = q[3 * qi + 1]; qz = q[3 * qi + 2];
        q2 = qx * qx + qy * qy + qz * qz;
    }
    float bd[KNN]; int bi[KNN];
#pragma unroll
    for (int k = 0; k < KNN; k++) { bd[k] = BIGF; bi[k] = 0; }

    for (int tb = base; tb < end; tb += TILE) {
        int cnt = min(TILE, end - tb);
        for (int i = threadIdx.x; i < cnt; i += BLOCK) {
            int j = tb + i;
            float rx = r[3 * j], ry = r[3 * j + 1], rz = r[3 * j + 2];
            lds[i] = make_float4(rx, ry, rz, rx * rx + ry * ry + rz * rz);
        }
        __syncthreads();
        scan_tile(lds, cnt, tb, qx, qy, qz, q2, bd, bi);
        __syncthreads();
    }
    if (qi < N) {
        float* od = wsd + ((size_t)qi * S + s) * KNN;
        int*   oi = wsi + ((size_t)qi * S + s) * KNN;
#pragma unroll
        for (int k = 0; k < KNN; k++) { od[k] = bd[k]; oi[k] = bi[k]; }
    }
}

// Merge S partial top-8 lists -> global top-8 -> IDW output.
__global__ __launch_bounds__(BLOCK) void knn_merge(
    const float* __restrict__ wsd, const int* __restrict__ wsi,
    const float* __restrict__ f, float* __restrict__ out, int N, int S) {
    int qi = blockIdx.x * BLOCK + threadIdx.x;
    if (qi >= N) return;
    float bd[KNN]; int bi[KNN];
#pragma unroll
    for (int k = 0; k < KNN; k++) { bd[k] = BIGF; bi[k] = 0; }
    const float* pd = wsd + (size_t)qi * S * KNN;
    const int*   pi = wsi + (size_t)qi * S * KNN;
    for (int c = 0; c < S * KNN; c++) {
        insert8(pd[c], pi[c], bd, bi);
    }
    float wsum = 0.f, ox = 0.f, oy = 0.f, oz = 0.f;
#pragma unroll
    for (int k = 0; k < KNN; k++) {
        float w = 1.0f / (fmaxf(bd[k], 0.0f) + EPSW);
        wsum += w;
        int j = bi[k];
        ox += w * f[3 * j];
        oy += w * f[3 * j + 1];
        oz += w * f[3 * j + 2];
    }
    float inv = 1.0f / wsum;
    out[3 * qi]     = ox * inv;
    out[3 * qi + 1] = oy * inv;
    out[3 * qi + 2] = oz * inv;
}

// Fallback: fused single-pass kernel (no workspace needed).
__global__ __launch_bounds__(BLOCK) void knn_fused(
    const float* __restrict__ q, const float* __restrict__ r,
    const float* __restrict__ f, float* __restrict__ out, int N, int M) {
    __shared__ float4 lds[TILE];
    int qi = blockIdx.x * BLOCK + threadIdx.x;
    float qx = 0.f, qy = 0.f, qz = 0.f, q2 = 0.f;
    if (qi < N) {
        qx = q[3 * qi]; qy = q[3 * qi + 1]; qz = q[3 * qi + 2];
        q2 = qx * qx + qy * qy + qz * qz;
    }
    float bd[KNN]; int bi[KNN];
#pragma unroll
    for (int k = 0; k < KNN; k++) { bd[k] = BIGF; bi[k] = 0; }

    for (int tb = 0; tb < M; tb += TILE) {
        int cnt = min(TILE, M - tb);
        for (int i = threadIdx.x; i < cnt; i += BLOCK) {
            int j = tb + i;
            float rx = r[3 * j], ry = r[3 * j + 1], rz = r[3 * j + 2];
            lds[i] = make_float4(rx, ry, rz, rx * rx + ry * ry + rz * rz);
        }
        __syncthreads();
        scan_tile(lds, cnt, tb, qx, qy, qz, q2, bd, bi);
        __syncthreads();
    }
    if (qi < N) {
        float wsum = 0.f, ox = 0.f, oy = 0.f, oz = 0.f;
#pragma unroll
        for (int k = 0; k < KNN; k++) {
            float w = 1.0f / (fmaxf(bd[k], 0.0f) + EPSW);
            wsum += w;
            int j = bi[k];
            ox += w * f[3 * j];
            oy += w * f[3 * j + 1];
            oz += w * f[3 * j + 2];
        }
        float inv = 1.0f / wsum;
        out[3 * qi]     = ox * inv;
        out[3 * qi + 1] = oy * inv;
        out[3 * qi + 2] = oz * inv;
    }
}

extern "C" void kernel_launch(void* const* d_in, const int* in_sizes, int n_in,
                              void* d_out, int out_size, void* d_ws, size_t ws_size,
                              hipStream_t stream) {
    const float* q = (const float*)d_in[0];
    const float* r = (const float*)d_in[1];
    const float* f = (const float*)d_in[2];
    float* out = (float*)d_out;
    int N = in_sizes[0] / 3;
    int M = in_sizes[1] / 3;

    int S = 8;  // M-splits for occupancy: 128*8 = 1024 blocks
    size_t need = (size_t)N * S * KNN * (sizeof(float) + sizeof(int));
    while (S > 1 && need > ws_size) { S >>= 1; need = (size_t)N * S * KNN * 8; }

    int grid_x = (N + BLOCK - 1) / BLOCK;
    if (need <= ws_size) {
        float* wsd = (float*)d_ws;
        int*   wsi = (int*)(wsd + (size_t)N * S * KNN);
        int chunk = (M + S - 1) / S;
        dim3 grid(grid_x, S);
        knn_partial<<<grid, BLOCK, 0, stream>>>(q, r, wsd, wsi, N, M, S, chunk);
        knn_merge<<<grid_x, BLOCK, 0, stream>>>(wsd, wsi, f, out, N, S);
    } else {
        knn_fused<<<grid_x, BLOCK, 0, stream>>>(q, r, f, out, N, M);
    }
}

// Round 3
// 354.135 us; speedup vs baseline: 1.4192x; 1.4192x over previous
//
#include <hip/hip_runtime.h>

#define KNN    8
#define BLOCK  256
#define TILE   2048
#define GROUP  64
#define EPSW   1e-8f
#define BIGF   3.4e38f

// Sorted-descending top-8 insert; all indices compile-time -> stays in VGPRs.
__device__ __forceinline__ void insert8(float d2, int j, float bd[KNN], int bi[KNN]) {
    if (d2 < bd[0]) {
        bd[0] = d2; bi[0] = j;
#pragma unroll
        for (int t = 0; t < KNN - 1; t++) {
            if (bd[t] < bd[t + 1]) {
                float td = bd[t]; bd[t] = bd[t + 1]; bd[t + 1] = td;
                int   ti = bi[t]; bi[t] = bi[t + 1]; bi[t + 1] = ti;
            }
        }
    }
}

// Precompute packed refs: (x, y, z, x^2+y^2+z^2).
__global__ __launch_bounds__(BLOCK) void prep_rp(const float* __restrict__ r,
                                                 float4* __restrict__ rp, int M) {
    int j = blockIdx.x * BLOCK + threadIdx.x;
    if (j < M) {
        float x = r[3 * j], y = r[3 * j + 1], z = r[3 * j + 2];
        rp[j] = make_float4(x, y, z, x * x + y * y + z * z);
    }
}

// Drain a 32-bit candidate mask: re-load, recompute exact d2, insert.
__device__ __forceinline__ void drain32(unsigned m, int gb, const float4* __restrict__ rp,
                                        float qx, float qy, float qz, float q2,
                                        float bd[KNN], int bi[KNN], float& thr) {
    while (m) {
        int b = __ffs(m) - 1;
        m &= m - 1;
        float4 p = rp[gb + b];
        float d2 = (q2 + p.w) - 2.0f * (qx * p.x + qy * p.y + qz * p.z);
        if (d2 < thr) {
            insert8(d2, gb + b, bd, bi);
            thr = bd[0];
        }
    }
}

// Partial kernel: blockIdx.y selects an M-chunk. Per-lane register bitmask
// defers the expensive insert chain; no LDS, no wave intrinsics.
__global__ __launch_bounds__(BLOCK) void knn_part3(
    const float4* __restrict__ rp, const float* __restrict__ q,
    float* __restrict__ wsd, int* __restrict__ wsi,
    int N, int M, int S, int chunk) {
    int tid = threadIdx.x;
    int qi = blockIdx.x * BLOCK + tid;
    if (qi >= N) return;
    int s = blockIdx.y;
    int base = s * chunk;
    int end = min(M, base + chunk);

    float qx = q[3 * qi], qy = q[3 * qi + 1], qz = q[3 * qi + 2];
    float q2 = qx * qx + qy * qy + qz * qz;

    float bd[KNN]; int bi[KNN];
#pragma unroll
    for (int k = 0; k < KNN; k++) { bd[k] = BIGF; bi[k] = 0; }
    float thr = BIGF;

    int g = base;
    for (; g + GROUP <= end; g += GROUP) {
        unsigned mlo = 0u, mhi = 0u;
#pragma unroll 2
        for (int u0 = 0; u0 < GROUP; u0 += 8) {
#pragma unroll
            for (int u = 0; u < 8; u++) {
                float4 p = rp[g + u0 + u];   // wave-uniform address -> 1 line/wave
                // EXACT reference numerics: (q2 + r2) - 2*(q . r)
                float d2 = (q2 + p.w) - 2.0f * (qx * p.x + qy * p.y + qz * p.z);
                unsigned bit = (d2 < thr) ? (1u << ((u0 + u) & 31)) : 0u;
                if (u0 + u < 32) mlo |= bit; else mhi |= bit;
            }
        }
        drain32(mlo, g,      rp, qx, qy, qz, q2, bd, bi, thr);
        drain32(mhi, g + 32, rp, qx, qy, qz, q2, bd, bi, thr);
    }
    for (; g < end; g++) {   // tail (chunk % 64 != 0 only)
        float4 p = rp[g];
        float d2 = (q2 + p.w) - 2.0f * (qx * p.x + qy * p.y + qz * p.z);
        if (d2 < thr) { insert8(d2, g, bd, bi); thr = bd[0]; }
    }

    float* od = wsd + ((size_t)qi * S + s) * KNN;
    int*   oi = wsi + ((size_t)qi * S + s) * KNN;
#pragma unroll
    for (int k = 0; k < KNN; k++) { od[k] = bd[k]; oi[k] = bi[k]; }
}

// Merge S partial top-8 lists -> global top-8 -> IDW output. (R1-proven.)
__global__ __launch_bounds__(BLOCK) void knn_merge(
    const float* __restrict__ wsd, const int* __restrict__ wsi,
    const float* __restrict__ f, float* __restrict__ out, int N, int S) {
    int qi = blockIdx.x * BLOCK + threadIdx.x;
    if (qi >= N) return;
    float bd[KNN]; int bi[KNN];
#pragma unroll
    for (int k = 0; k < KNN; k++) { bd[k] = BIGF; bi[k] = 0; }
    const float* pd = wsd + (size_t)qi * S * KNN;
    const int*   pi = wsi + (size_t)qi * S * KNN;
    for (int c = 0; c < S * KNN; c++) {
        insert8(pd[c], pi[c], bd, bi);
    }
    float wsum = 0.f, ox = 0.f, oy = 0.f, oz = 0.f;
#pragma unroll
    for (int k = 0; k < KNN; k++) {
        float w = 1.0f / (fmaxf(bd[k], 0.0f) + EPSW);
        wsum += w;
        int j = bi[k];
        ox += w * f[3 * j];
        oy += w * f[3 * j + 1];
        oz += w * f[3 * j + 2];
    }
    float inv = 1.0f / wsum;
    out[3 * qi]     = ox * inv;
    out[3 * qi + 1] = oy * inv;
    out[3 * qi + 2] = oz * inv;
}

// ---------- fallback (ws too small): R1 fused single-pass kernel ----------
__global__ __launch_bounds__(BLOCK) void knn_fused(
    const float* __restrict__ q, const float* __restrict__ r,
    const float* __restrict__ f, float* __restrict__ out, int N, int M) {
    __shared__ float4 lds[TILE];
    int qi = blockIdx.x * BLOCK + threadIdx.x;
    float qx = 0.f, qy = 0.f, qz = 0.f, q2 = 0.f;
    if (qi < N) {
        qx = q[3 * qi]; qy = q[3 * qi + 1]; qz = q[3 * qi + 2];
        q2 = qx * qx + qy * qy + qz * qz;
    }
    float bd[KNN]; int bi[KNN];
#pragma unroll
    for (int k = 0; k < KNN; k++) { bd[k] = BIGF; bi[k] = 0; }
    for (int tb = 0; tb < M; tb += TILE) {
        int cnt = min(TILE, M - tb);
        for (int i = threadIdx.x; i < cnt; i += BLOCK) {
            int j = tb + i;
            float rx = r[3 * j], ry = r[3 * j + 1], rz = r[3 * j + 2];
            lds[i] = make_float4(rx, ry, rz, rx * rx + ry * ry + rz * rz);
        }
        __syncthreads();
        for (int i = 0; i < cnt; i++) {
            float4 p = lds[i];
            float d2 = (q2 + p.w) - 2.0f * (qx * p.x + qy * p.y + qz * p.z);
            insert8(d2, tb + i, bd, bi);
        }
        __syncthreads();
    }
    if (qi < N) {
        float wsum = 0.f, ox = 0.f, oy = 0.f, oz = 0.f;
#pragma unroll
        for (int k = 0; k < KNN; k++) {
            float w = 1.0f / (fmaxf(bd[k], 0.0f) + EPSW);
            wsum += w;
            int j = bi[k];
            ox += w * f[3 * j];
            oy += w * f[3 * j + 1];
            oz += w * f[3 * j + 2];
        }
        float inv = 1.0f / wsum;
        out[3 * qi]     = ox * inv;
        out[3 * qi + 1] = oy * inv;
        out[3 * qi + 2] = oz * inv;
    }
}

extern "C" void kernel_launch(void* const* d_in, const int* in_sizes, int n_in,
                              void* d_out, int out_size, void* d_ws, size_t ws_size,
                              hipStream_t stream) {
    const float* q = (const float*)d_in[0];
    const float* r = (const float*)d_in[1];
    const float* f = (const float*)d_in[2];
    float* out = (float*)d_out;
    int N = in_sizes[0] / 3;
    int M = in_sizes[1] / 3;

    int S = 8;  // M-splits: 128*8 = 1024 blocks -> 4 blocks/CU
    size_t need = (size_t)M * 16 + (size_t)N * S * KNN * 8;
    while (S > 1 && need > ws_size) { S >>= 1; need = (size_t)M * 16 + (size_t)N * S * KNN * 8; }

    int grid_x = (N + BLOCK - 1) / BLOCK;
    if (need <= ws_size) {
        float4* rp = (float4*)d_ws;
        float* wsd = (float*)((char*)d_ws + (size_t)M * 16);
        int*   wsi = (int*)(wsd + (size_t)N * S * KNN);
        int chunk = (M + S - 1) / S;
        prep_rp<<<(M + BLOCK - 1) / BLOCK, BLOCK, 0, stream>>>(r, rp, M);
        dim3 grid(grid_x, S);
        knn_part3<<<grid, BLOCK, 0, stream>>>(rp, q, wsd, wsi, N, M, S, chunk);
        knn_merge<<<grid_x, BLOCK, 0, stream>>>(wsd, wsi, f, out, N, S);
    } else {
        knn_fused<<<grid_x, BLOCK, 0, stream>>>(q, r, f, out, N, M);
    }
}